// Round 5
// baseline (105.271 us; speedup 1.0000x reference)
//
#include <hip/hip_runtime.h>
#include <math.h>

#define NB 8
#define NH 3
#define NBH 24
#define NP 4096
#define BLK 256
#define RPB 32             // rows per block; 4 waves each cover 16 supertiles (1024 cols)
#define ROWBLKS (NP / RPB) // 128

typedef _Float16 half4 __attribute__((ext_vector_type(4)));
typedef _Float16 half8 __attribute__((ext_vector_type(8)));
typedef float floatx16 __attribute__((ext_vector_type(16)));

// Forced v_min3_f32 (3-input min; no -ffast-math so compiler won't fuse).
#define MIN3(r, a, b) asm("v_min3_f32 %0, %0, %1, %2" : "+v"(r) : "v"(a), "v"(b))

// MFMA with C = inline constant 0 (inline consts are legal in any src
// field). This frees the 16-reg crsq C-operand: rsq[row] is constant
// along the min axis, so min_c(rsq+part) = rsq + min_c(part) — rsq is
// added once in the epilogue (before the clamp: max(rsq+min, 0), exact).
#define MFMA16Z(d, a, bb) \
    asm("v_mfma_f32_32x32x16_f16 %0, %1, %2, 0" : "=&v"(d) : "v"(a), "v"(bb))

// Prep: for each (b,h), reflect all 4096 points and pack per-column
// [-2c0,-2c1,-2c2,csq] as 4xf16 into the workspace (24 x 32KB = 768KB,
// fits every XCD's 4MB L2). Done once per (b,h); the hot kernel just
// streams it. Block 0 wave 3 computes the regularizer and plain-stores
// out[0] (chamfer atomicAdds on top afterwards).
__global__ void __launch_bounds__(256) prep_kernel(const float* __restrict__ pts,
                                                   const float* __restrict__ planes,
                                                   _Float16* __restrict__ qg,
                                                   float* __restrict__ out) {
    const int tid = threadIdx.x;
    const int bh  = blockIdx.x >> 4;      // 384 blocks, 16 per (b,h)
    const int b   = bh / NH;

    const float* pl = planes + bh * 4;
    float n0 = pl[0], n1 = pl[1], n2 = pl[2], off = pl[3];
    float inv = 1.0f / sqrtf(n0 * n0 + n1 * n1 + n2 * n2);
    n0 *= inv; n1 *= inv; n2 *= inv;

    const float* bp = pts + (size_t)b * NP * 3;
    const int i = (blockIdx.x & 15) * 256 + tid;
    {
        float y0 = bp[i * 3 + 0], y1 = bp[i * 3 + 1], y2 = bp[i * 3 + 2];
        float t = 2.0f * (n0 * y0 + n1 * y1 + n2 * y2 + off);
        y0 -= t * n0; y1 -= t * n1; y2 -= t * n2;
        float csq = y0 * y0 + y1 * y1 + y2 * y2;
        half4 q = { (_Float16)(-2.0f * y0), (_Float16)(-2.0f * y1),
                    (_Float16)(-2.0f * y2), (_Float16)csq };
        *(half4*)(qg + ((size_t)bh * NP + i) * 4) = q;
    }

    if (blockIdx.x == 0 && tid >= 192) {   // reg loss on wave 3
        const int l = tid - 192;
        float r = 0.0f;
        if (l < NB) {
            float n[NH][3];
            for (int hh = 0; hh < NH; ++hh) {
                const float* p2 = planes + (l * NH + hh) * 4;
                float a0 = p2[0], a1 = p2[1], a2 = p2[2];
                float iv = 1.0f / sqrtf(a0 * a0 + a1 * a1 + a2 * a2);
                n[hh][0] = a0 * iv; n[hh][1] = a1 * iv; n[hh][2] = a2 * iv;
            }
            float fro = 0.0f;
            for (int i2 = 0; i2 < NH; ++i2)
                for (int j = 0; j < NH; ++j) {
                    float d = n[i2][0] * n[j][0] + n[i2][1] * n[j][1] + n[i2][2] * n[j][2]
                              - (i2 == j ? 1.0f : 0.0f);
                    fro += d * d;
                }
            r = 25.0f * sqrtf(fro);
        }
        for (int o = 32; o; o >>= 1) r += __shfl_down(r, o);
        if (l == 0) out[0] = r;
    }
}

// SYMMETRY: reflection is an affine isometric involution => the distance
// matrix is symmetric => cham_x == cham_y; compute row-mins once, double.
//
// v5: latency-bubble attack. Round-0 counters showed MFMA 23.5% + pure
// VALU ~18% — neither pipe half-busy; the time is MFMA->min3 exposed
// latency at too-low wave count. Changes vs v4:
//  (a) 2 d-pairs restored (consume stile u while u+1 is in the pipe);
//  (b) C-operand eliminated via MFMA-with-inline-0 + rsq-in-epilogue
//      (-16 regs crsq, -16 shfl setup) => in-loop live ~114, fits the
//      (256,4) 128-reg cap WITH slack (v2/v3 lesson: cap < live = 300MB
//      scratch disaster; here slack is positive);
//  (c) RPB=32: 4 waves x 16-supertile column quarters, grid (128,24) =
//      3072 blocks = 12/CU demanded, 4 resident (4 waves/SIMD) => 3
//      clean generations, ~50% occupancy vs round-0's 22.7%, finer tail.
// No barrier until the 512B rowmin combine. B fragments (raw half8 =
// two packed cols, even k=0..3 / odd k=4..7) stream from the L2-resident
// prep table; upper half-wave duplicates lines (its A k=8..15 are zero,
// annihilating the duplicate B content). Loads run 4 stiles (~300cyc)
// ahead of use => covers L2 latency.
__global__ void __launch_bounds__(BLK, 4) chamfer_mfma(const float* __restrict__ pts,
                                                       const _Float16* __restrict__ qg,
                                                       float* __restrict__ out) {
    __shared__ float rowmin[4][RPB];

    const int tid  = threadIdx.x;
    const int lane = tid & 63;
    const int wave = tid >> 6;
    const int bh   = blockIdx.y;
    const int b    = bh / NH;
    const int h    = lane >> 5;

    const float* bp = pts + (size_t)b * NP * 3;

    // A fragments: rows = ORIGINAL points. All 4 waves share the same 32
    // rows (each wave owns a column quarter). rsqv kept as ONE live reg.
    const int row = blockIdx.x * RPB + (lane & 31);
    float a0 = bp[row * 3 + 0], a1 = bp[row * 3 + 1], a2 = bp[row * 3 + 2];
    float rsqv = a0 * a0 + a1 * a1 + a2 * a2;
    half8 Aev = {0, 0, 0, 0, 0, 0, 0, 0};
    half8 Aod = {0, 0, 0, 0, 0, 0, 0, 0};
    if (lane < 32) {
        Aev[0] = (_Float16)a0; Aev[1] = (_Float16)a1;
        Aev[2] = (_Float16)a2; Aev[3] = (_Float16)1.0f;
        Aod[4] = (_Float16)a0; Aod[5] = (_Float16)a1;
        Aod[6] = (_Float16)a2; Aod[7] = (_Float16)1.0f;
    }

    float rm[16];
    #pragma unroll
    for (int j = 0; j < 16; ++j) rm[j] = 1e30f;

    // supertile u (64 cols): lane reads cols u*64 + {2l, 2l+1} as one dwordx4
    const _Float16* bcol = qg + (size_t)bh * NP * 4 + (lane & 31) * 8;
    const int U0 = wave * 16;
    #define LD(u) (*(const half8*)(bcol + (size_t)(u) * 256))

    half8 c0 = LD(U0), c1 = LD(U0 + 1), c2 = LD(U0 + 2), c3 = LD(U0 + 3);
    floatx16 dA0, dA1, dB0, dB1;
    MFMA16Z(dA0, Aev, c0);  MFMA16Z(dA1, Aod, c0);   // st U0
    MFMA16Z(dB0, Aev, c1);  MFMA16Z(dB1, Aod, c1);   // st U0+1

    #pragma unroll 1
    for (int u = U0; u < U0 + 12; u += 4) {
        c0 = LD(u + 4);
        #pragma unroll
        for (int j = 0; j < 16; ++j) MIN3(rm[j], dA0[j], dA1[j]);   // st u
        MFMA16Z(dA0, Aev, c2);  MFMA16Z(dA1, Aod, c2);              // st u+2
        c1 = LD(u + 5);
        #pragma unroll
        for (int j = 0; j < 16; ++j) MIN3(rm[j], dB0[j], dB1[j]);   // st u+1
        MFMA16Z(dB0, Aev, c3);  MFMA16Z(dB1, Aod, c3);              // st u+3
        c2 = LD(u + 6);
        #pragma unroll
        for (int j = 0; j < 16; ++j) MIN3(rm[j], dA0[j], dA1[j]);   // st u+2
        MFMA16Z(dA0, Aev, c0);  MFMA16Z(dA1, Aod, c0);              // st u+4
        c3 = LD(u + 7);
        #pragma unroll
        for (int j = 0; j < 16; ++j) MIN3(rm[j], dB0[j], dB1[j]);   // st u+3
        MFMA16Z(dB0, Aev, c1);  MFMA16Z(dB1, Aod, c1);              // st u+5
    }
    {   // after loop: dA=st U0+12, dB=st U0+13, c2=st U0+14, c3=st U0+15
        #pragma unroll
        for (int j = 0; j < 16; ++j) MIN3(rm[j], dA0[j], dA1[j]);   // st U0+12
        MFMA16Z(dA0, Aev, c2);  MFMA16Z(dA1, Aod, c2);              // st U0+14
        #pragma unroll
        for (int j = 0; j < 16; ++j) MIN3(rm[j], dB0[j], dB1[j]);   // st U0+13
        MFMA16Z(dB0, Aev, c3);  MFMA16Z(dB1, Aod, c3);              // st U0+15
        #pragma unroll
        for (int j = 0; j < 16; ++j) MIN3(rm[j], dA0[j], dA1[j]);   // st U0+14
        #pragma unroll
        for (int j = 0; j < 16; ++j) MIN3(rm[j], dB0[j], dB1[j]);   // st U0+15
    }
    #undef LD

    // min across the 32 lanes (cols) sharing each row, within this quarter
    #pragma unroll
    for (int j = 0; j < 16; ++j) {
        float v = rm[j];
        v = fminf(v, __shfl_xor(v, 1));
        v = fminf(v, __shfl_xor(v, 2));
        v = fminf(v, __shfl_xor(v, 4));
        v = fminf(v, __shfl_xor(v, 8));
        v = fminf(v, __shfl_xor(v, 16));
        rm[j] = v;
    }

    // publish per-row partial mins (constant j indexing only — runtime
    // indexing rm[] would go to scratch). rows: (j&3)+8*(j>>2)+4*h.
    if ((lane & 31) == 0) {
        #pragma unroll
        for (int j = 0; j < 16; ++j)
            rowmin[wave][(j & 3) + 8 * (j >> 2) + 4 * h] = rm[j];
    }
    __syncthreads();

    // combine 4 column quarters, add rsq, clamp, sum 32 rows, one atomic.
    // tid<32 is wave 0 lane tid => its rsqv belongs to row base+tid.
    if (tid < RPB) {
        float m = fminf(fminf(rowmin[0][tid], rowmin[1][tid]),
                        fminf(rowmin[2][tid], rowmin[3][tid]));
        float v = fmaxf(m + rsqv, 0.0f);
        #pragma unroll
        for (int o = 16; o; o >>= 1) v += __shfl_down(v, o, 32);
        if (tid == 0) atomicAdd(out, v * (2.0f / (float)(NB * NP)));
    }
}

extern "C" void kernel_launch(void* const* d_in, const int* in_sizes, int n_in,
                              void* d_out, int out_size, void* d_ws, size_t ws_size,
                              hipStream_t stream) {
    const float* planes = (const float*)d_in[0];  // (8,3,4) fp32
    const float* pts    = (const float*)d_in[1];  // (8,4096,3) fp32
    float* out          = (float*)d_out;
    _Float16* qg        = (_Float16*)d_ws;        // needs 24*4096*8 = 768 KB

    prep_kernel<<<384, 256, 0, stream>>>(pts, planes, qg, out);

    dim3 grid(ROWBLKS, NBH);
    chamfer_mfma<<<grid, BLK, 0, stream>>>(pts, qg, out);
}

// Round 6
// 88.057 us; speedup vs baseline: 1.1955x; 1.1955x over previous
//
#include <hip/hip_runtime.h>
#include <math.h>

#define NB 8
#define NH 3
#define NBH 24
#define NP 4096
#define BLK 256
#define RPB 64             // rows per block; 4 waves = 2 rowgroups x 2 col-halves
#define ROWBLKS (NP / RPB) // 64

typedef _Float16 half4 __attribute__((ext_vector_type(4)));
typedef _Float16 half8 __attribute__((ext_vector_type(8)));
typedef float floatx16 __attribute__((ext_vector_type(16)));

// Forced v_min3_f32 (3-input min; no -ffast-math so compiler won't fuse).
#define MIN3(r, a, b) asm("v_min3_f32 %0, %0, %1, %2" : "+v"(r) : "v"(a), "v"(b))

// MFMA with C = inline constant 0 (verified HW-correct in r5, absmax 0.0).
// rsq[row] is constant along the min axis: min_c(rsq+part) = rsq+min_c(part),
// added once in the epilogue before the clamp. Saves the 16-reg C operand.
#define MFMA16Z(d, a, bb) \
    asm("v_mfma_f32_32x32x16_f16 %0, %1, %2, 0" : "=&v"(d) : "v"(a), "v"(bb))

// Prep: for each (b,h), reflect all 4096 points and pack per-column
// [-2c0,-2c1,-2c2,csq] as 4xf16 into the workspace (24 x 32KB = 768KB).
// Done once per (b,h); chamfer blocks bulk-copy their slice to LDS (the
// reflect VALU would otherwise be 64x redundant at RPB=64). Block 0
// wave 3 computes the regularizer and plain-stores out[0].
__global__ void __launch_bounds__(256) prep_kernel(const float* __restrict__ pts,
                                                   const float* __restrict__ planes,
                                                   _Float16* __restrict__ qg,
                                                   float* __restrict__ out) {
    const int tid = threadIdx.x;
    const int bh  = blockIdx.x >> 4;      // 384 blocks, 16 per (b,h)
    const int b   = bh / NH;

    const float* pl = planes + bh * 4;
    float n0 = pl[0], n1 = pl[1], n2 = pl[2], off = pl[3];
    float inv = 1.0f / sqrtf(n0 * n0 + n1 * n1 + n2 * n2);
    n0 *= inv; n1 *= inv; n2 *= inv;

    const float* bp = pts + (size_t)b * NP * 3;
    const int i = (blockIdx.x & 15) * 256 + tid;
    {
        float y0 = bp[i * 3 + 0], y1 = bp[i * 3 + 1], y2 = bp[i * 3 + 2];
        float t = 2.0f * (n0 * y0 + n1 * y1 + n2 * y2 + off);
        y0 -= t * n0; y1 -= t * n1; y2 -= t * n2;
        float csq = y0 * y0 + y1 * y1 + y2 * y2;
        half4 q = { (_Float16)(-2.0f * y0), (_Float16)(-2.0f * y1),
                    (_Float16)(-2.0f * y2), (_Float16)csq };
        *(half4*)(qg + ((size_t)bh * NP + i) * 4) = q;
    }

    if (blockIdx.x == 0 && tid >= 192) {   // reg loss on wave 3
        const int l = tid - 192;
        float r = 0.0f;
        if (l < NB) {
            float n[NH][3];
            for (int hh = 0; hh < NH; ++hh) {
                const float* p2 = planes + (l * NH + hh) * 4;
                float a0 = p2[0], a1 = p2[1], a2 = p2[2];
                float iv = 1.0f / sqrtf(a0 * a0 + a1 * a1 + a2 * a2);
                n[hh][0] = a0 * iv; n[hh][1] = a1 * iv; n[hh][2] = a2 * iv;
            }
            float fro = 0.0f;
            for (int i2 = 0; i2 < NH; ++i2)
                for (int j = 0; j < NH; ++j) {
                    float d = n[i2][0] * n[j][0] + n[i2][1] * n[j][1] + n[i2][2] * n[j][2]
                              - (i2 == j ? 1.0f : 0.0f);
                    fro += d * d;
                }
            r = 25.0f * sqrtf(fro);
        }
        for (int o = 32; o; o >>= 1) r += __shfl_down(r, o);
        if (l == 0) out[0] = r;
    }
}

// SYMMETRY: reflection is an affine isometric involution => the distance
// matrix is symmetric => cham_x == cham_y; row-mins once, doubled.
//
// v6 = merge of all verified wins; L2-streaming REFUTED by r4/r5
// (exposed 250-500cyc L2/L3 latency per stile at 2-4 waves/SIMD; r5:
// MfmaUtil 9.6% = exactly the MFMA content, both pipes idle). Back to
// the r0/r1-proven LDS source (ds_read_b128 ~120cyc, high BW):
//  - block copies its 32KB prep-table slice to LDS (pure vectorized
//    copy, 8 iters/thread — no reflect math, unlike r0/r1);
//  - r5's verified lean core: 2 d-pairs, MFMA C=0, rsq in epilogue
//    (in-loop live ~111 regs < 128 cap of (256,4) => no spill);
//  - RPB=64: 4 waves = 2 rowgroups x 2 col-halves (32 stiles each);
//    grid (64,24)=1536; LDS 33.5KB and ~111 VGPR both => 4 blocks/CU
//    = 4 waves/SIMD (1.33x r1) with finer tail;
//  - one barrier before the loop, 512B rowmin combine after.
__global__ void __launch_bounds__(BLK, 4) chamfer_mfma(const float* __restrict__ pts,
                                                       const _Float16* __restrict__ qg,
                                                       float* __restrict__ out) {
    __shared__ _Float16 qcols[NP * 4];   // 32 KB staged slice
    __shared__ float rsqbuf[RPB];
    __shared__ float rowmin[2][RPB];

    const int tid  = threadIdx.x;
    const int lane = tid & 63;
    const int wave = tid >> 6;
    const int bh   = blockIdx.y;
    const int b    = bh / NH;
    const int rw   = wave & 1;   // row group (rows rw*32..rw*32+31)
    const int cw   = wave >> 1;  // column half (stiles cw*32..cw*32+31)
    const int h    = lane >> 5;

    // bulk copy: 32KB slice qg[bh] -> qcols (2048 half8s, 8 per thread)
    {
        const half8* src = (const half8*)(qg + (size_t)bh * NP * 4);
        half8* dst = (half8*)qcols;
        #pragma unroll
        for (int i = 0; i < 8; ++i) dst[tid + i * BLK] = src[tid + i * BLK];
    }

    // A fragments: rows = ORIGINAL points (pts is L3-resident, 384KB).
    const float* bp = pts + (size_t)b * NP * 3;
    const int row = blockIdx.x * RPB + rw * 32 + (lane & 31);
    float a0 = bp[row * 3 + 0], a1 = bp[row * 3 + 1], a2 = bp[row * 3 + 2];
    float rsqv = a0 * a0 + a1 * a1 + a2 * a2;
    half8 Aev = {0, 0, 0, 0, 0, 0, 0, 0};
    half8 Aod = {0, 0, 0, 0, 0, 0, 0, 0};
    if (lane < 32) {
        Aev[0] = (_Float16)a0; Aev[1] = (_Float16)a1;
        Aev[2] = (_Float16)a2; Aev[3] = (_Float16)1.0f;
        Aod[4] = (_Float16)a0; Aod[5] = (_Float16)a1;
        Aod[6] = (_Float16)a2; Aod[7] = (_Float16)1.0f;
    }
    if (cw == 0 && lane < 32) rsqbuf[rw * 32 + (lane & 31)] = rsqv;
    __syncthreads();   // staging + rsqbuf complete

    float rm[16];
    #pragma unroll
    for (int j = 0; j < 16; ++j) rm[j] = 1e30f;

    // supertile u (64 cols): lane reads cols u*64 + {2l, 2l+1} as one b128.
    // Upper half-wave reads the same address (broadcast, free); its B
    // k=8..15 content is annihilated by A's zero k=8..15.
    const _Float16* bcol = &qcols[(lane & 31) * 8];
    const int U0 = cw * 32;
    #define LD(u) (*(const half8*)(bcol + (u) * 256))

    half8 c0 = LD(U0), c1 = LD(U0 + 1), c2 = LD(U0 + 2), c3 = LD(U0 + 3);
    floatx16 dA0, dA1, dB0, dB1;
    MFMA16Z(dA0, Aev, c0);  MFMA16Z(dA1, Aod, c0);   // st U0
    MFMA16Z(dB0, Aev, c1);  MFMA16Z(dB1, Aod, c1);   // st U0+1

    // Each iter consumes stiles u..u+3, issues u+2..u+5, loads u+4..u+7.
    #pragma unroll 1
    for (int u = U0; u < U0 + 28; u += 4) {
        c0 = LD(u + 4);
        #pragma unroll
        for (int j = 0; j < 16; ++j) MIN3(rm[j], dA0[j], dA1[j]);   // st u
        MFMA16Z(dA0, Aev, c2);  MFMA16Z(dA1, Aod, c2);              // st u+2
        c1 = LD(u + 5);
        #pragma unroll
        for (int j = 0; j < 16; ++j) MIN3(rm[j], dB0[j], dB1[j]);   // st u+1
        MFMA16Z(dB0, Aev, c3);  MFMA16Z(dB1, Aod, c3);              // st u+3
        c2 = LD(u + 6);
        #pragma unroll
        for (int j = 0; j < 16; ++j) MIN3(rm[j], dA0[j], dA1[j]);   // st u+2
        MFMA16Z(dA0, Aev, c0);  MFMA16Z(dA1, Aod, c0);              // st u+4
        c3 = LD(u + 7);
        #pragma unroll
        for (int j = 0; j < 16; ++j) MIN3(rm[j], dB0[j], dB1[j]);   // st u+3
        MFMA16Z(dB0, Aev, c1);  MFMA16Z(dB1, Aod, c1);              // st u+5
    }
    {   // after loop: dA=st U0+28, dB=st U0+29, c2=st U0+30, c3=st U0+31
        #pragma unroll
        for (int j = 0; j < 16; ++j) MIN3(rm[j], dA0[j], dA1[j]);   // st U0+28
        MFMA16Z(dA0, Aev, c2);  MFMA16Z(dA1, Aod, c2);              // st U0+30
        #pragma unroll
        for (int j = 0; j < 16; ++j) MIN3(rm[j], dB0[j], dB1[j]);   // st U0+29
        MFMA16Z(dB0, Aev, c3);  MFMA16Z(dB1, Aod, c3);              // st U0+31
        #pragma unroll
        for (int j = 0; j < 16; ++j) MIN3(rm[j], dA0[j], dA1[j]);   // st U0+30
        #pragma unroll
        for (int j = 0; j < 16; ++j) MIN3(rm[j], dB0[j], dB1[j]);   // st U0+31
    }
    #undef LD

    // min across the 32 lanes (cols) sharing each row, within this half
    #pragma unroll
    for (int j = 0; j < 16; ++j) {
        float v = rm[j];
        v = fminf(v, __shfl_xor(v, 1));
        v = fminf(v, __shfl_xor(v, 2));
        v = fminf(v, __shfl_xor(v, 4));
        v = fminf(v, __shfl_xor(v, 8));
        v = fminf(v, __shfl_xor(v, 16));
        rm[j] = v;
    }

    // publish per-row partial mins (constant j indexing only; lanes 0 and
    // 32 publish — h=0/1 cover rows (j&3)+8*(j>>2) and +4).
    if ((lane & 31) == 0) {
        #pragma unroll
        for (int j = 0; j < 16; ++j)
            rowmin[cw][rw * 32 + (j & 3) + 8 * (j >> 2) + 4 * h] = rm[j];
    }
    __syncthreads();

    // combine col-halves, add rsq, clamp, sum 64 rows, one atomic/block
    if (tid < RPB) {
        float m = fminf(rowmin[0][tid], rowmin[1][tid]);
        float v = fmaxf(m + rsqbuf[tid], 0.0f);
        #pragma unroll
        for (int o = 32; o; o >>= 1) v += __shfl_down(v, o);
        if (tid == 0) atomicAdd(out, v * (2.0f / (float)(NB * NP)));
    }
}

extern "C" void kernel_launch(void* const* d_in, const int* in_sizes, int n_in,
                              void* d_out, int out_size, void* d_ws, size_t ws_size,
                              hipStream_t stream) {
    const float* planes = (const float*)d_in[0];  // (8,3,4) fp32
    const float* pts    = (const float*)d_in[1];  // (8,4096,3) fp32
    float* out          = (float*)d_out;
    _Float16* qg        = (_Float16*)d_ws;        // needs 24*4096*8 = 768 KB

    prep_kernel<<<384, 256, 0, stream>>>(pts, planes, qg, out);

    dim3 grid(ROWBLKS, NBH);
    chamfer_mfma<<<grid, BLK, 0, stream>>>(pts, qg, out);
}

// Round 7
// 79.046 us; speedup vs baseline: 1.3318x; 1.1140x over previous
//
#include <hip/hip_runtime.h>
#include <math.h>

#define NB 8
#define NH 3
#define NBH 24
#define NP 4096
#define BLK 256
#define RPB 128              // rows per block: 4 waves x 32 rows, each wave all 64 stiles
#define ROWBLKS (NP / RPB)   // 32
#define NPART (ROWBLKS * NBH) // 768 partials in d_ws

typedef _Float16 half8 __attribute__((ext_vector_type(8)));
typedef float floatx16 __attribute__((ext_vector_type(16)));

// Forced v_min3_f32 (3-input min; no -ffast-math so compiler won't fuse).
#define MIN3(r, a, b) asm("v_min3_f32 %0, %0, %1, %2" : "+v"(r) : "v"(a), "v"(b))

// MFMA with C = inline constant 0 (verified HW-correct r5/r6, absmax 0.0).
// rsq[row] is constant along the min axis: min_c(rsq+part)=rsq+min_c(part);
// rsq added once in the epilogue before the clamp. Saves the 16-reg C operand.
#define MFMA16Z(d, a, bb) \
    asm("v_mfma_f32_32x32x16_f16 %0, %1, %2, 0" : "=&v"(d) : "v"(a), "v"(bb))

// SYMMETRY: reflection is an affine isometric involution => the distance
// matrix is symmetric => cham_x == cham_y; row-mins once, doubled (r1+).
//
// v7: remove per-block serializers. Evidence: R5 (3072 blocks) 47.8us,
// R4/R6 (1536) ~30us, R1 (768) ~25us — residual scales with block count
// and launch structure, not inner-loop quality (pipe content is ~4us;
// R5's MfmaUtil 9.6% == MFMA content smeared 10x). Changes:
//  - ONE worker dispatch, grid (32,24)=768 blocks = 3/CU, residency cap 4
//    => single generation, no tail;
//  - NO atomics: block plain-stores 1 partial to d_ws; finalize (1 block)
//    reduces + adds regularizer => deletes 768 same-address atomicAdds
//    AND the init-ordering kernel AND the prep dispatch;
//  - staging reflect done in-block (R0-proven; ~0.9us chip-wide VALU);
//  - R0's deep 4-pair MFMA pipeline (best measured: 20.4us/pass) with
//    the r5/r6 lean core (MFMA C=0, rsq via shfl) => ~115 live regs,
//    fits (256,4)'s 128 cap with slack (r2/r3 lesson: cap<live = 300MB
//    scratch disaster; r6 same core compiled clean).
__global__ void __launch_bounds__(BLK, 4) chamfer_mfma(const float* __restrict__ pts,
                                                       const float* __restrict__ planes,
                                                       float* __restrict__ partials) {
    __shared__ _Float16 qcols[NP * 4];   // 32 KB: per col [-2c0,-2c1,-2c2,csq]
    __shared__ float bsum[4];

    const int tid  = threadIdx.x;
    const int lane = tid & 63;
    const int wave = tid >> 6;
    const int bh   = blockIdx.y;
    const int b    = bh / NH;
    const int h    = lane >> 5;

    const float* pl = planes + bh * 4;
    float n0 = pl[0], n1 = pl[1], n2 = pl[2], off = pl[3];
    float inv = 1.0f / sqrtf(n0 * n0 + n1 * n1 + n2 * n2);
    n0 *= inv; n1 *= inv; n2 *= inv;

    const float* bp = pts + (size_t)b * NP * 3;

    // stage 4096 reflected cols (R0/R1-proven pattern)
    for (int i = tid; i < NP; i += BLK) {
        float y0 = bp[i * 3 + 0], y1 = bp[i * 3 + 1], y2 = bp[i * 3 + 2];
        float t = 2.0f * (n0 * y0 + n1 * y1 + n2 * y2 + off);
        y0 -= t * n0; y1 -= t * n1; y2 -= t * n2;
        float csq = y0 * y0 + y1 * y1 + y2 * y2;
        _Float16* q = &qcols[i * 4];
        q[0] = (_Float16)(-2.0f * y0); q[1] = (_Float16)(-2.0f * y1);
        q[2] = (_Float16)(-2.0f * y2); q[3] = (_Float16)csq;
    }

    // A fragments: rows = ORIGINAL points; wave w owns rows w*32..w*32+31.
    // All lanes load their row (dup across halves) so rsq is shuffle-able.
    const int row = blockIdx.x * RPB + wave * 32 + (lane & 31);
    float a0 = bp[row * 3 + 0], a1 = bp[row * 3 + 1], a2 = bp[row * 3 + 2];
    float rsqv = a0 * a0 + a1 * a1 + a2 * a2;
    half8 Aev = {0, 0, 0, 0, 0, 0, 0, 0};
    half8 Aod = {0, 0, 0, 0, 0, 0, 0, 0};
    if (lane < 32) {
        Aev[0] = (_Float16)a0; Aev[1] = (_Float16)a1;
        Aev[2] = (_Float16)a2; Aev[3] = (_Float16)1.0f;
        Aod[4] = (_Float16)a0; Aod[5] = (_Float16)a1;
        Aod[6] = (_Float16)a2; Aod[7] = (_Float16)1.0f;
    }
    __syncthreads();   // staging complete

    float rm[16];
    #pragma unroll
    for (int j = 0; j < 16; ++j) rm[j] = 1e30f;

    // supertile u (64 cols): lane reads cols u*64 + {2l, 2l+1} as one b128.
    // Upper half-wave reads the same address (broadcast, free); its B
    // k=8..15 content is annihilated by A's zero k=8..15.
    const _Float16* bcol = &qcols[(lane & 31) * 8];
    #define LD(u) (*(const half8*)(bcol + (u) * 256))

    half8 c0 = LD(0), c1 = LD(1), c2 = LD(2), c3 = LD(3);
    floatx16 dA0, dA1, dB0, dB1;
    MFMA16Z(dA0, Aev, c0);  MFMA16Z(dA1, Aod, c0);   // st 0
    MFMA16Z(dB0, Aev, c1);  MFMA16Z(dB1, Aod, c1);   // st 1

    // R0's 4-pair schedule: loads ~4 stiles ahead, min3 ~2 stiles behind.
    #pragma unroll 1
    for (int u = 4; u <= 60; u += 4) {
        c0 = LD(u);
        #pragma unroll
        for (int j = 0; j < 16; ++j) MIN3(rm[j], dA0[j], dA1[j]);   // st u-4
        MFMA16Z(dA0, Aev, c2);  MFMA16Z(dA1, Aod, c2);              // st u-2
        c1 = LD(u + 1);
        #pragma unroll
        for (int j = 0; j < 16; ++j) MIN3(rm[j], dB0[j], dB1[j]);   // st u-3
        MFMA16Z(dB0, Aev, c3);  MFMA16Z(dB1, Aod, c3);              // st u-1
        c2 = LD(u + 2);
        #pragma unroll
        for (int j = 0; j < 16; ++j) MIN3(rm[j], dA0[j], dA1[j]);   // st u-2
        MFMA16Z(dA0, Aev, c0);  MFMA16Z(dA1, Aod, c0);              // st u
        c3 = LD(u + 3);
        #pragma unroll
        for (int j = 0; j < 16; ++j) MIN3(rm[j], dB0[j], dB1[j]);   // st u-1
        MFMA16Z(dB0, Aev, c1);  MFMA16Z(dB1, Aod, c1);              // st u+1
    }
    {   // epilogue: st 62, 63 issue + drain (st 60..63 consumed here)
        #pragma unroll
        for (int j = 0; j < 16; ++j) MIN3(rm[j], dA0[j], dA1[j]);   // st 60
        MFMA16Z(dA0, Aev, c2);  MFMA16Z(dA1, Aod, c2);              // st 62
        #pragma unroll
        for (int j = 0; j < 16; ++j) MIN3(rm[j], dB0[j], dB1[j]);   // st 61
        MFMA16Z(dB0, Aev, c3);  MFMA16Z(dB1, Aod, c3);              // st 63
        #pragma unroll
        for (int j = 0; j < 16; ++j) MIN3(rm[j], dA0[j], dA1[j]);   // st 62
        #pragma unroll
        for (int j = 0; j < 16; ++j) MIN3(rm[j], dB0[j], dB1[j]);   // st 63
    }
    #undef LD

    // min across the 32 lanes (cols) sharing each row — xor-reduce leaves
    // the group min in every lane of the 32-group.
    #pragma unroll
    for (int j = 0; j < 16; ++j) {
        float v = rm[j];
        v = fminf(v, __shfl_xor(v, 1));
        v = fminf(v, __shfl_xor(v, 2));
        v = fminf(v, __shfl_xor(v, 4));
        v = fminf(v, __shfl_xor(v, 8));
        v = fminf(v, __shfl_xor(v, 16));
        rm[j] = v;
    }

    // add rsq (shfl from the lane owning that row), clamp, sum this
    // half-wave's 16 rows (replicated across its 32 lanes — fine, we
    // pick lane 0 / 32 below).
    float s = 0.0f;
    #pragma unroll
    for (int j = 0; j < 16; ++j) {
        float rsqj = __shfl(rsqv, (j & 3) + 8 * (j >> 2) + 4 * h);
        s += fmaxf(rm[j] + rsqj, 0.0f);   // clamp after min: exact
    }
    s += __shfl_xor(s, 32);   // combine the two 16-row halves of the wave

    if (lane == 0) bsum[wave] = s;
    __syncthreads();
    if (tid == 0)
        partials[blockIdx.y * ROWBLKS + blockIdx.x] =
            bsum[0] + bsum[1] + bsum[2] + bsum[3];
}

// 1 block: reduce 768 partials, compute regularizer, single store to out.
// No atomics anywhere; no ordering constraint vs the worker kernel.
__global__ void __launch_bounds__(256) finalize(const float* __restrict__ planes,
                                                const float* __restrict__ partials,
                                                float* __restrict__ out) {
    __shared__ float acc[4];
    const int tid = threadIdx.x;
    float s = partials[tid] + partials[tid + 256] + partials[tid + 512];
    #pragma unroll
    for (int o = 32; o; o >>= 1) s += __shfl_down(s, o);
    if ((tid & 63) == 0) acc[tid >> 6] = s;
    __syncthreads();
    if (tid == 0) {
        float cham = (acc[0] + acc[1] + acc[2] + acc[3]) * (2.0f / (float)(NB * NP));
        float reg = 0.0f;
        for (int bb = 0; bb < NB; ++bb) {
            float n[NH][3];
            for (int hh = 0; hh < NH; ++hh) {
                const float* p2 = planes + (bb * NH + hh) * 4;
                float a0 = p2[0], a1 = p2[1], a2 = p2[2];
                float iv = 1.0f / sqrtf(a0 * a0 + a1 * a1 + a2 * a2);
                n[hh][0] = a0 * iv; n[hh][1] = a1 * iv; n[hh][2] = a2 * iv;
            }
            float fro = 0.0f;
            for (int i = 0; i < NH; ++i)
                for (int j = 0; j < NH; ++j) {
                    float d = n[i][0] * n[j][0] + n[i][1] * n[j][1] + n[i][2] * n[j][2]
                              - (i == j ? 1.0f : 0.0f);
                    fro += d * d;
                }
            reg += 25.0f * sqrtf(fro);
        }
        out[0] = cham + reg;
    }
}

extern "C" void kernel_launch(void* const* d_in, const int* in_sizes, int n_in,
                              void* d_out, int out_size, void* d_ws, size_t ws_size,
                              hipStream_t stream) {
    const float* planes = (const float*)d_in[0];  // (8,3,4) fp32
    const float* pts    = (const float*)d_in[1];  // (8,4096,3) fp32
    float* out          = (float*)d_out;
    float* partials     = (float*)d_ws;           // 768 floats

    dim3 grid(ROWBLKS, NBH);
    chamfer_mfma<<<grid, BLK, 0, stream>>>(pts, planes, partials);
    finalize<<<1, 256, 0, stream>>>(planes, partials, out);
}

// Round 8
// 78.299 us; speedup vs baseline: 1.3445x; 1.0095x over previous
//
#include <hip/hip_runtime.h>
#include <math.h>

#define NB 8
#define NH 3
#define NBH 24
#define NP 4096
#define BLK 256
#define RPB 128              // rows per block: 4 waves x 32 rows, each wave all 64 stiles
#define ROWBLKS (NP / RPB)   // 32
#define NPART (ROWBLKS * NBH) // 768 partials in d_ws

typedef _Float16 half4 __attribute__((ext_vector_type(4)));
typedef _Float16 half8 __attribute__((ext_vector_type(8)));
typedef float floatx16 __attribute__((ext_vector_type(16)));

// Forced v_min3_f32 (3-input min; no -ffast-math so compiler won't fuse).
#define MIN3(r, a, b) asm("v_min3_f32 %0, %0, %1, %2" : "+v"(r) : "v"(a), "v"(b))

// MFMA with C = inline constant 0 (verified HW-correct r5-r7, absmax 0.0).
// rsq[row] is constant along the min axis: min_c(rsq+part)=rsq+min_c(part);
// rsq added once in the epilogue before the clamp. Saves the 16-reg C operand.
#define MFMA16Z(d, a, bb) \
    asm("v_mfma_f32_32x32x16_f16 %0, %1, %2, 0" : "=&v"(d) : "v"(a), "v"(bb))

// SYMMETRY: reflection is an affine isometric involution => the distance
// matrix is symmetric => cham_x == cham_y; row-mins once, doubled.
//
// v8 = v7 + cycle trims. CLOCK FINDING (r5 counters): implied core clock
// during our kernels is ~0.7-1.0 GHz, not 2.4 — the 268MB memory-bound
// poison fill (41us, VALU 4%) parks DVFS and we run before ramp-up. That
// explains why five structurally different designs all plateaued at
// 25-30us against a ~9us @2.4GHz issue-content model (~27us @0.8GHz).
// Only lever left: fewer cycles. Trims:
//  - staging store = ONE ds_write_b64 (half4) instead of 4 scalar b16;
//  - A-row global loads hoisted ABOVE staging (HBM latency hidden under
//    the staging loop instead of exposed before the barrier);
//  - staging loop unrolled 4x (12 outstanding global loads);
//  - LDS XOR-deswizzle REJECTED on analysis: 32 lanes x 16B = 512B/read
//    > 128B/cyc LDS width => >=4 lanes/bank/phase under ANY bijection;
//    the 4-way conflict is a bandwidth floor, not a mapping artifact.
// Kept from v7: 768 blocks single generation, no atomics, partials +
// tiny finalize (2 dispatches is the floor: out[0] must be re-inited
// every iteration, and cross-block init ordering needs a dispatch edge).
__global__ void __launch_bounds__(BLK, 4) chamfer_mfma(const float* __restrict__ pts,
                                                       const float* __restrict__ planes,
                                                       float* __restrict__ partials) {
    __shared__ _Float16 qcols[NP * 4];   // 32 KB: per col [-2c0,-2c1,-2c2,csq]
    __shared__ float bsum[4];

    const int tid  = threadIdx.x;
    const int lane = tid & 63;
    const int wave = tid >> 6;
    const int bh   = blockIdx.y;
    const int b    = bh / NH;
    const int h    = lane >> 5;

    const float* pl = planes + bh * 4;
    float n0 = pl[0], n1 = pl[1], n2 = pl[2], off = pl[3];
    float inv = 1.0f / sqrtf(n0 * n0 + n1 * n1 + n2 * n2);
    n0 *= inv; n1 *= inv; n2 *= inv;

    const float* bp = pts + (size_t)b * NP * 3;

    // A-row loads issued FIRST: their ~500cyc latency hides under staging.
    const int row = blockIdx.x * RPB + wave * 32 + (lane & 31);
    float a0 = bp[row * 3 + 0], a1 = bp[row * 3 + 1], a2 = bp[row * 3 + 2];

    // stage 4096 reflected cols; one b64 LDS store per column
    #pragma unroll 4
    for (int i = tid; i < NP; i += BLK) {
        float y0 = bp[i * 3 + 0], y1 = bp[i * 3 + 1], y2 = bp[i * 3 + 2];
        float t = 2.0f * (n0 * y0 + n1 * y1 + n2 * y2 + off);
        y0 -= t * n0; y1 -= t * n1; y2 -= t * n2;
        float csq = y0 * y0 + y1 * y1 + y2 * y2;
        half4 q = { (_Float16)(-2.0f * y0), (_Float16)(-2.0f * y1),
                    (_Float16)(-2.0f * y2), (_Float16)csq };
        *(half4*)&qcols[i * 4] = q;
    }

    // A fragments: rows = ORIGINAL points; wave w owns rows w*32..w*32+31.
    // All lanes load their row (dup across halves) so rsq is shuffle-able.
    float rsqv = a0 * a0 + a1 * a1 + a2 * a2;
    half8 Aev = {0, 0, 0, 0, 0, 0, 0, 0};
    half8 Aod = {0, 0, 0, 0, 0, 0, 0, 0};
    if (lane < 32) {
        Aev[0] = (_Float16)a0; Aev[1] = (_Float16)a1;
        Aev[2] = (_Float16)a2; Aev[3] = (_Float16)1.0f;
        Aod[4] = (_Float16)a0; Aod[5] = (_Float16)a1;
        Aod[6] = (_Float16)a2; Aod[7] = (_Float16)1.0f;
    }
    __syncthreads();   // staging complete

    float rm[16];
    #pragma unroll
    for (int j = 0; j < 16; ++j) rm[j] = 1e30f;

    // supertile u (64 cols): lane reads cols u*64 + {2l, 2l+1} as one b128.
    // Upper half-wave reads the same address (broadcast, free); its B
    // k=8..15 content is annihilated by A's zero k=8..15.
    const _Float16* bcol = &qcols[(lane & 31) * 8];
    #define LD(u) (*(const half8*)(bcol + (u) * 256))

    half8 c0 = LD(0), c1 = LD(1), c2 = LD(2), c3 = LD(3);
    floatx16 dA0, dA1, dB0, dB1;
    MFMA16Z(dA0, Aev, c0);  MFMA16Z(dA1, Aod, c0);   // st 0
    MFMA16Z(dB0, Aev, c1);  MFMA16Z(dB1, Aod, c1);   // st 1

    // 4-pair schedule: loads ~4 stiles ahead, min3 ~2 stiles behind.
    #pragma unroll 1
    for (int u = 4; u <= 60; u += 4) {
        c0 = LD(u);
        #pragma unroll
        for (int j = 0; j < 16; ++j) MIN3(rm[j], dA0[j], dA1[j]);   // st u-4
        MFMA16Z(dA0, Aev, c2);  MFMA16Z(dA1, Aod, c2);              // st u-2
        c1 = LD(u + 1);
        #pragma unroll
        for (int j = 0; j < 16; ++j) MIN3(rm[j], dB0[j], dB1[j]);   // st u-3
        MFMA16Z(dB0, Aev, c3);  MFMA16Z(dB1, Aod, c3);              // st u-1
        c2 = LD(u + 2);
        #pragma unroll
        for (int j = 0; j < 16; ++j) MIN3(rm[j], dA0[j], dA1[j]);   // st u-2
        MFMA16Z(dA0, Aev, c0);  MFMA16Z(dA1, Aod, c0);              // st u
        c3 = LD(u + 3);
        #pragma unroll
        for (int j = 0; j < 16; ++j) MIN3(rm[j], dB0[j], dB1[j]);   // st u-1
        MFMA16Z(dB0, Aev, c1);  MFMA16Z(dB1, Aod, c1);              // st u+1
    }
    {   // epilogue: st 62, 63 issue + drain (st 60..63 consumed here)
        #pragma unroll
        for (int j = 0; j < 16; ++j) MIN3(rm[j], dA0[j], dA1[j]);   // st 60
        MFMA16Z(dA0, Aev, c2);  MFMA16Z(dA1, Aod, c2);              // st 62
        #pragma unroll
        for (int j = 0; j < 16; ++j) MIN3(rm[j], dB0[j], dB1[j]);   // st 61
        MFMA16Z(dB0, Aev, c3);  MFMA16Z(dB1, Aod, c3);              // st 63
        #pragma unroll
        for (int j = 0; j < 16; ++j) MIN3(rm[j], dA0[j], dA1[j]);   // st 62
        #pragma unroll
        for (int j = 0; j < 16; ++j) MIN3(rm[j], dB0[j], dB1[j]);   // st 63
    }
    #undef LD

    // min across the 32 lanes (cols) sharing each row — xor-reduce leaves
    // the group min in every lane of the 32-group.
    #pragma unroll
    for (int j = 0; j < 16; ++j) {
        float v = rm[j];
        v = fminf(v, __shfl_xor(v, 1));
        v = fminf(v, __shfl_xor(v, 2));
        v = fminf(v, __shfl_xor(v, 4));
        v = fminf(v, __shfl_xor(v, 8));
        v = fminf(v, __shfl_xor(v, 16));
        rm[j] = v;
    }

    // add rsq (shfl from the lane owning that row), clamp, sum this
    // half-wave's 16 rows.
    float s = 0.0f;
    #pragma unroll
    for (int j = 0; j < 16; ++j) {
        float rsqj = __shfl(rsqv, (j & 3) + 8 * (j >> 2) + 4 * h);
        s += fmaxf(rm[j] + rsqj, 0.0f);   // clamp after min: exact
    }
    s += __shfl_xor(s, 32);   // combine the two 16-row halves of the wave

    if (lane == 0) bsum[wave] = s;
    __syncthreads();
    if (tid == 0)
        partials[blockIdx.y * ROWBLKS + blockIdx.x] =
            bsum[0] + bsum[1] + bsum[2] + bsum[3];
}

// 1 block: reduce 768 partials, compute regularizer, single store to out.
// No atomics anywhere; no ordering constraint vs the worker kernel.
__global__ void __launch_bounds__(256) finalize(const float* __restrict__ planes,
                                                const float* __restrict__ partials,
                                                float* __restrict__ out) {
    __shared__ float acc[4];
    const int tid = threadIdx.x;
    float s = partials[tid] + partials[tid + 256] + partials[tid + 512];
    #pragma unroll
    for (int o = 32; o; o >>= 1) s += __shfl_down(s, o);
    if ((tid & 63) == 0) acc[tid >> 6] = s;
    __syncthreads();
    if (tid == 0) {
        float cham = (acc[0] + acc[1] + acc[2] + acc[3]) * (2.0f / (float)(NB * NP));
        float reg = 0.0f;
        for (int bb = 0; bb < NB; ++bb) {
            float n[NH][3];
            for (int hh = 0; hh < NH; ++hh) {
                const float* p2 = planes + (bb * NH + hh) * 4;
                float a0 = p2[0], a1 = p2[1], a2 = p2[2];
                float iv = 1.0f / sqrtf(a0 * a0 + a1 * a1 + a2 * a2);
                n[hh][0] = a0 * iv; n[hh][1] = a1 * iv; n[hh][2] = a2 * iv;
            }
            float fro = 0.0f;
            for (int i = 0; i < NH; ++i)
                for (int j = 0; j < NH; ++j) {
                    float d = n[i][0] * n[j][0] + n[i][1] * n[j][1] + n[i][2] * n[j][2]
                              - (i == j ? 1.0f : 0.0f);
                    fro += d * d;
                }
            reg += 25.0f * sqrtf(fro);
        }
        out[0] = cham + reg;
    }
}

extern "C" void kernel_launch(void* const* d_in, const int* in_sizes, int n_in,
                              void* d_out, int out_size, void* d_ws, size_t ws_size,
                              hipStream_t stream) {
    const float* planes = (const float*)d_in[0];  // (8,3,4) fp32
    const float* pts    = (const float*)d_in[1];  // (8,4096,3) fp32
    float* out          = (float*)d_out;
    float* partials     = (float*)d_ws;           // 768 floats

    dim3 grid(ROWBLKS, NBH);
    chamfer_mfma<<<grid, BLK, 0, stream>>>(pts, planes, partials);
    finalize<<<1, 256, 0, stream>>>(planes, partials, out);
}

// Round 9
// 77.870 us; speedup vs baseline: 1.3519x; 1.0055x over previous
//
#include <hip/hip_runtime.h>
#include <math.h>

#define NB 8
#define NH 3
#define NBH 24
#define NP 4096
#define BLK 256
#define RPB 128              // rows per block: 4 waves x 32 rows, each wave all cols
#define ROWBLKS (NP / RPB)   // 32
#define NPART (ROWBLKS * NBH) // 768 partials in d_ws

typedef _Float16 half4 __attribute__((ext_vector_type(4)));
typedef _Float16 half8 __attribute__((ext_vector_type(8)));
typedef float floatx16 __attribute__((ext_vector_type(16)));

// Forced v_min3_f32 (3-input min; no -ffast-math so compiler won't fuse).
#define MIN3(r, a, b) asm("v_min3_f32 %0, %0, %1, %2" : "+v"(r) : "v"(a), "v"(b))

// MFMA with C = inline constant 0 (verified HW-correct r5-r8, absmax 0.0).
#define MFMA16Z(d, a, bb) \
    asm("v_mfma_f32_32x32x16_f16 %0, %1, %2, 0" : "=&v"(d) : "v"(a), "v"(bb))

// SYMMETRY: reflection is an affine isometric involution => the distance
// matrix is symmetric => cham_x == cham_y; row-mins once, doubled.
//
// v9: FULL-K B packing. Previously lanes 32-63 read duplicate LDS lines
// and their B k=8-15 content was annihilated (K-usage 4/16, 64 ds_reads
// per wave). Now each 128-col supertile packs 4 columns per B col-slot:
// quarter q lives in k=4q..4q+3, selected by 4 complementary A masks
// (Aev/Aod live in lanes<32 = A k0-7; Ae2/Ao2 live in lanes>=32 = A
// k8-15). Per supertile: ONE ds_read_b128 (64 lanes x contiguous 16B =
// 1KB, 8 clean 128B beats, zero bank conflicts) + 4 MFMA + 32 min3.
// ds_read count HALVES (64->32); MFMA/min3 unchanged (output-bound:
// 1024 distances/MFMA, 2 values/min3 — both at their floor). Bit-
// identical result (same products; min is order-independent).
// Clock finding (r5/r0 counter cross-check): kernels run at ~1 GHz
// (DVFS parked by the 41us memory-bound poison fill), idling 60-77% on
// latency — hence attacking latency-event count, not pipe content.
// (256,3): grid 768 = 3 blocks/CU regardless, so the 170-reg cap is
// free slack against spills (r2/r3 disaster mode).
__global__ void __launch_bounds__(BLK, 3) chamfer_mfma(const float* __restrict__ pts,
                                                       const float* __restrict__ planes,
                                                       float* __restrict__ partials) {
    __shared__ _Float16 qcols[NP * 4];   // 32 KB: per col [-2c0,-2c1,-2c2,csq]
    __shared__ float bsum[4];

    const int tid  = threadIdx.x;
    const int lane = tid & 63;
    const int wave = tid >> 6;
    const int bh   = blockIdx.y;
    const int b    = bh / NH;
    const int h    = lane >> 5;

    const float* pl = planes + bh * 4;
    float n0 = pl[0], n1 = pl[1], n2 = pl[2], off = pl[3];
    float inv = 1.0f / sqrtf(n0 * n0 + n1 * n1 + n2 * n2);
    n0 *= inv; n1 *= inv; n2 *= inv;

    const float* bp = pts + (size_t)b * NP * 3;

    // A-row loads issued FIRST: their latency hides under staging.
    const int row = blockIdx.x * RPB + wave * 32 + (lane & 31);
    float a0 = bp[row * 3 + 0], a1 = bp[row * 3 + 1], a2 = bp[row * 3 + 2];

    // stage 4096 reflected cols; one b64 LDS store per column
    #pragma unroll 4
    for (int i = tid; i < NP; i += BLK) {
        float y0 = bp[i * 3 + 0], y1 = bp[i * 3 + 1], y2 = bp[i * 3 + 2];
        float t = 2.0f * (n0 * y0 + n1 * y1 + n2 * y2 + off);
        y0 -= t * n0; y1 -= t * n1; y2 -= t * n2;
        float csq = y0 * y0 + y1 * y1 + y2 * y2;
        half4 q = { (_Float16)(-2.0f * y0), (_Float16)(-2.0f * y1),
                    (_Float16)(-2.0f * y2), (_Float16)csq };
        *(half4*)&qcols[i * 4] = q;
    }

    // A fragments, 4 quarter-masks. A layout (32x32x16): lanes 0-31 hold
    // k0-7, lanes 32-63 hold k8-15. Each mask is [r0,r1,r2,1] in its
    // 4-k quarter, zero elsewhere — selects one packed column quarter.
    float rsqv = a0 * a0 + a1 * a1 + a2 * a2;
    half8 Aev = {0, 0, 0, 0, 0, 0, 0, 0};   // quarter 0: k0-3  (lanes<32)
    half8 Aod = {0, 0, 0, 0, 0, 0, 0, 0};   // quarter 1: k4-7  (lanes<32)
    half8 Ae2 = {0, 0, 0, 0, 0, 0, 0, 0};   // quarter 2: k8-11 (lanes>=32)
    half8 Ao2 = {0, 0, 0, 0, 0, 0, 0, 0};   // quarter 3: k12-15(lanes>=32)
    if (lane < 32) {
        Aev[0] = (_Float16)a0; Aev[1] = (_Float16)a1;
        Aev[2] = (_Float16)a2; Aev[3] = (_Float16)1.0f;
        Aod[4] = (_Float16)a0; Aod[5] = (_Float16)a1;
        Aod[6] = (_Float16)a2; Aod[7] = (_Float16)1.0f;
    } else {
        Ae2[0] = (_Float16)a0; Ae2[1] = (_Float16)a1;
        Ae2[2] = (_Float16)a2; Ae2[3] = (_Float16)1.0f;
        Ao2[4] = (_Float16)a0; Ao2[5] = (_Float16)a1;
        Ao2[6] = (_Float16)a2; Ao2[7] = (_Float16)1.0f;
    }
    __syncthreads();   // staging complete

    float rm[16];
    #pragma unroll
    for (int j = 0; j < 16; ++j) rm[j] = 1e30f;

    // supertile k = 128 cols. Lane l reads 16B at byte k*1024 +
    // (l&31)*32 + (l>>5)*16: col-slot c=l&31 covers global cols
    // 4c..4c+3; lanes<32 carry cols 4c,4c+1 (k0-7), lanes>=32 carry
    // 4c+2,4c+3 (k8-15). 64 lanes x contiguous 16B = the full 1KB stile.
    const _Float16* bcol = &qcols[(lane & 31) * 16 + (lane >> 5) * 8];
    #define LDS128(k) (*(const half8*)(bcol + (k) * 512))

    half8 c0 = LDS128(0), c1 = LDS128(1), c2 = LDS128(2), c3 = LDS128(3);
    floatx16 dA0, dA1, dB0, dB1;
    MFMA16Z(dA0, Aev, c0);  MFMA16Z(dA1, Aod, c0);   // st0 q01
    MFMA16Z(dB0, Ae2, c0);  MFMA16Z(dB1, Ao2, c0);   // st0 q23

    // Invariant at iter k: c0..c3 = stiles k-4..k-1; dA/dB = stile k-4.
    // Per iter: 4 stiles consumed+issued, 4 loads. Proven r8 skeleton.
    #pragma unroll 1
    for (int k = 4; k <= 28; k += 4) {
        c0 = LDS128(k);
        #pragma unroll
        for (int j = 0; j < 16; ++j) MIN3(rm[j], dA0[j], dA1[j]);   // st k-4 q01
        MFMA16Z(dA0, Aev, c1);  MFMA16Z(dA1, Aod, c1);              // st k-3 q01
        #pragma unroll
        for (int j = 0; j < 16; ++j) MIN3(rm[j], dB0[j], dB1[j]);   // st k-4 q23
        MFMA16Z(dB0, Ae2, c1);  MFMA16Z(dB1, Ao2, c1);              // st k-3 q23
        c1 = LDS128(k + 1);
        #pragma unroll
        for (int j = 0; j < 16; ++j) MIN3(rm[j], dA0[j], dA1[j]);   // st k-3 q01
        MFMA16Z(dA0, Aev, c2);  MFMA16Z(dA1, Aod, c2);              // st k-2 q01
        #pragma unroll
        for (int j = 0; j < 16; ++j) MIN3(rm[j], dB0[j], dB1[j]);   // st k-3 q23
        MFMA16Z(dB0, Ae2, c2);  MFMA16Z(dB1, Ao2, c2);              // st k-2 q23
        c2 = LDS128(k + 2);
        #pragma unroll
        for (int j = 0; j < 16; ++j) MIN3(rm[j], dA0[j], dA1[j]);   // st k-2 q01
        MFMA16Z(dA0, Aev, c3);  MFMA16Z(dA1, Aod, c3);              // st k-1 q01
        #pragma unroll
        for (int j = 0; j < 16; ++j) MIN3(rm[j], dB0[j], dB1[j]);   // st k-2 q23
        MFMA16Z(dB0, Ae2, c3);  MFMA16Z(dB1, Ao2, c3);              // st k-1 q23
        c3 = LDS128(k + 3);
        #pragma unroll
        for (int j = 0; j < 16; ++j) MIN3(rm[j], dA0[j], dA1[j]);   // st k-1 q01
        MFMA16Z(dA0, Aev, c0);  MFMA16Z(dA1, Aod, c0);              // st k   q01
        #pragma unroll
        for (int j = 0; j < 16; ++j) MIN3(rm[j], dB0[j], dB1[j]);   // st k-1 q23
        MFMA16Z(dB0, Ae2, c0);  MFMA16Z(dB1, Ao2, c0);              // st k   q23
    }
    {   // exit: c0..c3 = st28..31, dA/dB = st28. Drain st28..31.
        #pragma unroll
        for (int j = 0; j < 16; ++j) MIN3(rm[j], dA0[j], dA1[j]);   // st28 q01
        MFMA16Z(dA0, Aev, c1);  MFMA16Z(dA1, Aod, c1);              // st29 q01
        #pragma unroll
        for (int j = 0; j < 16; ++j) MIN3(rm[j], dB0[j], dB1[j]);   // st28 q23
        MFMA16Z(dB0, Ae2, c1);  MFMA16Z(dB1, Ao2, c1);              // st29 q23
        #pragma unroll
        for (int j = 0; j < 16; ++j) MIN3(rm[j], dA0[j], dA1[j]);   // st29 q01
        MFMA16Z(dA0, Aev, c2);  MFMA16Z(dA1, Aod, c2);              // st30 q01
        #pragma unroll
        for (int j = 0; j < 16; ++j) MIN3(rm[j], dB0[j], dB1[j]);   // st29 q23
        MFMA16Z(dB0, Ae2, c2);  MFMA16Z(dB1, Ao2, c2);              // st30 q23
        #pragma unroll
        for (int j = 0; j < 16; ++j) MIN3(rm[j], dA0[j], dA1[j]);   // st30 q01
        MFMA16Z(dA0, Aev, c3);  MFMA16Z(dA1, Aod, c3);              // st31 q01
        #pragma unroll
        for (int j = 0; j < 16; ++j) MIN3(rm[j], dB0[j], dB1[j]);   // st30 q23
        MFMA16Z(dB0, Ae2, c3);  MFMA16Z(dB1, Ao2, c3);              // st31 q23
        #pragma unroll
        for (int j = 0; j < 16; ++j) MIN3(rm[j], dA0[j], dA1[j]);   // st31 q01
        #pragma unroll
        for (int j = 0; j < 16; ++j) MIN3(rm[j], dB0[j], dB1[j]);   // st31 q23
    }
    #undef LDS128

    // min across the 32 col-slots sharing each row — xor-reduce leaves
    // the group min in every lane of the 32-group.
    #pragma unroll
    for (int j = 0; j < 16; ++j) {
        float v = rm[j];
        v = fminf(v, __shfl_xor(v, 1));
        v = fminf(v, __shfl_xor(v, 2));
        v = fminf(v, __shfl_xor(v, 4));
        v = fminf(v, __shfl_xor(v, 8));
        v = fminf(v, __shfl_xor(v, 16));
        rm[j] = v;
    }

    // add rsq (shfl from the lane owning that row), clamp, sum this
    // half-wave's 16 rows (D rows: (j&3)+8*(j>>2)+4*h).
    float s = 0.0f;
    #pragma unroll
    for (int j = 0; j < 16; ++j) {
        float rsqj = __shfl(rsqv, (j & 3) + 8 * (j >> 2) + 4 * h);
        s += fmaxf(rm[j] + rsqj, 0.0f);   // clamp after min: exact
    }
    s += __shfl_xor(s, 32);   // combine the two 16-row halves of the wave

    if (lane == 0) bsum[wave] = s;
    __syncthreads();
    if (tid == 0)
        partials[blockIdx.y * ROWBLKS + blockIdx.x] =
            bsum[0] + bsum[1] + bsum[2] + bsum[3];
}

// 1 block: reduce 768 partials, compute regularizer, single store to out.
// No atomics anywhere; no ordering constraint vs the worker kernel.
__global__ void __launch_bounds__(256) finalize(const float* __restrict__ planes,
                                                const float* __restrict__ partials,
                                                float* __restrict__ out) {
    __shared__ float acc[4];
    const int tid = threadIdx.x;
    float s = partials[tid] + partials[tid + 256] + partials[tid + 512];
    #pragma unroll
    for (int o = 32; o; o >>= 1) s += __shfl_down(s, o);
    if ((tid & 63) == 0) acc[tid >> 6] = s;
    __syncthreads();
    if (tid == 0) {
        float cham = (acc[0] + acc[1] + acc[2] + acc[3]) * (2.0f / (float)(NB * NP));
        float reg = 0.0f;
        for (int bb = 0; bb < NB; ++bb) {
            float n[NH][3];
            for (int hh = 0; hh < NH; ++hh) {
                const float* p2 = planes + (bb * NH + hh) * 4;
                float a0 = p2[0], a1 = p2[1], a2 = p2[2];
                float iv = 1.0f / sqrtf(a0 * a0 + a1 * a1 + a2 * a2);
                n[hh][0] = a0 * iv; n[hh][1] = a1 * iv; n[hh][2] = a2 * iv;
            }
            float fro = 0.0f;
            for (int i = 0; i < NH; ++i)
                for (int j = 0; j < NH; ++j) {
                    float d = n[i][0] * n[j][0] + n[i][1] * n[j][1] + n[i][2] * n[j][2]
                              - (i == j ? 1.0f : 0.0f);
                    fro += d * d;
                }
            reg += 25.0f * sqrtf(fro);
        }
        out[0] = cham + reg;
    }
}

extern "C" void kernel_launch(void* const* d_in, const int* in_sizes, int n_in,
                              void* d_out, int out_size, void* d_ws, size_t ws_size,
                              hipStream_t stream) {
    const float* planes = (const float*)d_in[0];  // (8,3,4) fp32
    const float* pts    = (const float*)d_in[1];  // (8,4096,3) fp32
    float* out          = (float*)d_out;
    float* partials     = (float*)d_ws;           // 768 floats

    dim3 grid(ROWBLKS, NBH);
    chamfer_mfma<<<grid, BLK, 0, stream>>>(pts, planes, partials);
    finalize<<<1, 256, 0, stream>>>(planes, partials, out);
}